// Round 18
// baseline (1166.248 us; speedup 1.0000x reference)
//
#include <hip/hip_runtime.h>
#include <hip/hip_bf16.h>

#define LAYERS 5
#define STATS_NB 16
#define EMAX 160

typedef __attribute__((ext_vector_type(8))) short short8v;
typedef __attribute__((ext_vector_type(4))) float f32x4;
typedef __attribute__((ext_vector_type(2))) float f32x2;
typedef __attribute__((ext_vector_type(4))) unsigned int u32x4;

#define MFMA(a, b, c) __builtin_amdgcn_mfma_f32_16x16x32_bf16(a, b, c, 0, 0, 0)

__device__ __forceinline__ void atomAddF(float* p, float v) {
    __hip_atomic_fetch_add(p, v, __ATOMIC_RELAXED, __HIP_MEMORY_SCOPE_AGENT);
}

// ---- bf16 helpers ----
__device__ __forceinline__ float b2f(unsigned short u) { return __uint_as_float(((unsigned)u) << 16); }
__device__ __forceinline__ unsigned short f2b(float f) {
    __hip_bfloat16 h = __float2bfloat16(f);
    unsigned short u;
    __builtin_memcpy(&u, &h, 2);
    return u;
}
__device__ __forceinline__ void st4(unsigned short* p, float4 v) {
    ushort4 u;
    u.x = f2b(v.x); u.y = f2b(v.y); u.z = f2b(v.z); u.w = f2b(v.w);
    *(ushort4*)p = u;
}
// unpack one u32 (2 packed bf16) to f32x2
__device__ __forceinline__ f32x2 up2(unsigned int w) {
    f32x2 v;
    v.x = __uint_as_float(w << 16);
    v.y = __uint_as_float(w & 0xffff0000u);
    return v;
}

// h[i] = atom_emb[x[i*9]]  (bf16 store)
__global__ void init_h_kernel(const int* __restrict__ x, const float* __restrict__ atom_emb,
                              unsigned short* __restrict__ h, int N) {
    int tid = blockIdx.x * blockDim.x + threadIdx.x;
    if (tid >= N * 32) return;
    int i = tid >> 5;
    int c4 = (tid & 31) << 2;
    int a = x[i * 9];
    float4 v = *(const float4*)(atom_emb + a * 128 + c4);
    st4(h + (size_t)i * 128 + c4, v);
}

// ---------------- CSR build (once per call) ----------------
__global__ void hist_kernel(const int* __restrict__ ei, int* __restrict__ cnt, int E) {
    int e = blockIdx.x * blockDim.x + threadIdx.x;
    if (e < E) atomicAdd(&cnt[ei[E + e]], 1);
}

__global__ void scan_block_sum(const int* __restrict__ cnt, int* __restrict__ bsum, int N) {
    __shared__ int ls[256];
    int base = blockIdx.x * 1024;
    int tid = threadIdx.x;
    int s = 0;
#pragma unroll
    for (int j = 0; j < 4; ++j) {
        int i = base + tid * 4 + j;
        if (i < N) s += cnt[i];
    }
    ls[tid] = s;
    __syncthreads();
    for (int off = 128; off > 0; off >>= 1) {
        if (tid < off) ls[tid] += ls[tid + off];
        __syncthreads();
    }
    if (tid == 0) bsum[blockIdx.x] = ls[0];
}

__global__ void scan_bsums(int* __restrict__ bsum, int nb) {
    if (blockIdx.x == 0 && threadIdx.x == 0) {
        int acc = 0;
        for (int i = 0; i < nb; ++i) { int v = bsum[i]; bsum[i] = acc; acc += v; }
    }
}

__global__ void scan_write(int* __restrict__ cnt_cursor, const int* __restrict__ bsum,
                           int* __restrict__ rowptr, int N, int E) {
    __shared__ int ls[256];
    int base = blockIdx.x * 1024;
    int tid = threadIdx.x;
    int v[4];
    int s = 0;
#pragma unroll
    for (int j = 0; j < 4; ++j) {
        int i = base + tid * 4 + j;
        v[j] = (i < N) ? cnt_cursor[i] : 0;
        s += v[j];
    }
    ls[tid] = s;
    __syncthreads();
    if (tid == 0) {
        int acc = 0;
        for (int i = 0; i < 256; ++i) { int t = ls[i]; ls[i] = acc; acc += t; }
    }
    __syncthreads();
    int off = bsum[blockIdx.x] + ls[tid];
#pragma unroll
    for (int j = 0; j < 4; ++j) {
        int i = base + tid * 4 + j;
        if (i < N) {
            rowptr[i] = off;
            cnt_cursor[i] = off;
            off += v[j];
        }
    }
    if (blockIdx.x == 0 && tid == 0) rowptr[N] = E;
}

// ebuf[pos] = src | bond<<19   (src < 2^19, bond < 8)
__global__ void scatter_kernel(const int* __restrict__ ei, const int* __restrict__ eattr,
                               int* __restrict__ cursor, int* __restrict__ ebuf, int E) {
    int e = blockIdx.x * blockDim.x + threadIdx.x;
    if (e >= E) return;
    int d = ei[E + e];
    int pos = atomicAdd(&cursor[d], 1);
    ebuf[pos] = ei[e] | (eattr[e * 3] << 19);
}

// ---------------- weight pre-pack (plain bf16 RNE, 16x16 fragment order) ----------------
__global__ void pack_w1_kernel(const float* __restrict__ W1, unsigned short* __restrict__ wh) {
    int tid = blockIdx.x * blockDim.x + threadIdx.x;
    if (tid >= LAYERS * 16 * 4 * 64) return;
    int lane = tid & 63;
    int ks = (tid >> 6) & 3;
    int nt = (tid >> 8) & 15;
    int l  = tid >> 12;
    int n  = nt * 16 + (lane & 15);
    int k0 = ks * 32 + ((lane >> 4) << 3);
    unsigned short hh[8];
#pragma unroll
    for (int j = 0; j < 8; ++j)
        hh[j] = f2b(W1[((size_t)l * 128 + k0 + j) * 256 + n]);
    size_t off = (size_t)tid * 8;
    *(ushort4*)(wh + off)     = make_ushort4(hh[0], hh[1], hh[2], hh[3]);
    *(ushort4*)(wh + off + 4) = make_ushort4(hh[4], hh[5], hh[6], hh[7]);
}

__global__ void pack_w2_kernel(const float* __restrict__ W2, unsigned short* __restrict__ wh) {
    int tid = blockIdx.x * blockDim.x + threadIdx.x;
    if (tid >= LAYERS * 8 * 8 * 64) return;
    int lane = tid & 63;
    int ks = (tid >> 6) & 7;
    int nt = (tid >> 9) & 7;
    int l  = tid >> 12;
    int n  = nt * 16 + (lane & 15);
    int k0 = ks * 32 + ((lane >> 4) << 3);
    unsigned short hh[8];
#pragma unroll
    for (int j = 0; j < 8; ++j)
        hh[j] = f2b(W2[((size_t)l * 256 + k0 + j) * 128 + n]);
    size_t off = (size_t)tid * 8;
    *(ushort4*)(wh + off)     = make_ushort4(hh[0], hh[1], hh[2], hh[3]);
    *(ushort4*)(wh + off + 4) = make_ushort4(hh[4], hh[5], hh[6], hh[7]);
}

// ---------------- fused per-layer kernel ----------------
// BM=64 rows/block, 512 threads (8 waves, 2M x 4N wave grid), 16x16x32 MFMA
// (4 independent acc chains per wave — 32x32 single-chain was slower, r13).
// Plain bf16 weights (single MFMA/fragment): absmax 0.656 < 0.75 (r16/r17 measured).
// Gather math in f32x2 (packed v_pk_fma/max dual-issue).
// NOTE: launch_bounds MUST stay (512,6). (512,8) caps VGPR+AGPR at 64 and this
// kernel's ~72-reg floor then spills: VGPR_Count drops to 32 and FETCH/WRITE
// balloon ~3x (confirmed twice: r11, r16).
template <bool FIRST>
__global__ __launch_bounds__(512, 6) void fused_mlp_kernel(
        const unsigned short* __restrict__ zin,
        const int* __restrict__ rowptr, const int* __restrict__ ebuf,
        const float* __restrict__ bond_emb,
        const float* __restrict__ stats_prev,
        const float* __restrict__ gamma_prev, const float* __restrict__ beta_prev,
        float invN, float clampv,
        const unsigned short* __restrict__ w1h,
        const unsigned short* __restrict__ w2h,
        const float* __restrict__ b1, const float* __restrict__ b2,
        unsigned short* __restrict__ zout, float* __restrict__ stats_out, int N) {
    __shared__ float bemb[8 * 128];
    __shared__ float scl[128], shl[128];
    __shared__ int els[EMAX];
    __shared__ int rp[65];
    __shared__ unsigned short xs[64][136];
    __shared__ unsigned short ts[64][136];

    int tid = threadIdx.x;
    int rowBase = blockIdx.x * 64;
    int lane = tid & 63;
    int wv = tid >> 6;          // 0..7

    // stage 1: bemb, raw stats sums, rowptr slice
    for (int i = tid; i < 1024; i += 512) bemb[i] = bond_emb[i];
    if (FIRST) {
        if (tid < 128) { scl[tid] = 1.f; shl[tid] = 0.f; }
    } else {
        if (tid < 256) {
            float s = 0.f;
#pragma unroll
            for (int i = 0; i < STATS_NB; ++i) s += stats_prev[i * 256 + tid];
            if (tid < 128) scl[tid] = s; else shl[tid - 128] = s;
        }
    }
    if (tid >= 256 && tid <= 320) {
        int t = tid - 256;
        int rr = rowBase + t;
        rp[t] = rowptr[rr < N ? rr : N];
    }
    __syncthreads();
    // stage 2: edge list; finalize BN affine
    int beg = rp[0];
    int cnt = rp[64] - beg;
    for (int i = tid; i < cnt && i < EMAX; i += 512) els[i] = ebuf[beg + i];
    if (!FIRST && tid < 128) {
        float S = scl[tid], Q = shl[tid];
        float mean = S * invN;
        float var = Q * invN - mean * mean;
        float sc = rsqrtf(var + 1e-5f) * gamma_prev[tid];
        scl[tid] = sc;
        shl[tid] = beta_prev[tid] - mean * sc;
    }
    __syncthreads();

    // phase 1: per-thread gather in packed f32x2. thread -> (row, 16-col chunk)
    {
        int r = tid >> 3;
        int c0 = (tid & 7) << 4;
        int row = rowBase + r;
        f32x2 xv[8];
        if (row < N) {
            const f32x2* sc2 = (const f32x2*)(scl + c0);
            const f32x2* sh2 = (const f32x2*)(shl + c0);
            f32x2 cl2; cl2.x = clampv; cl2.y = clampv;
            f32x2 zero2; zero2.x = 0.f; zero2.y = 0.f;
            {
                const unsigned short* hp = zin + (size_t)row * 128 + c0;
                u32x4 u0 = *(const u32x4*)hp;
                u32x4 u1 = *(const u32x4*)(hp + 8);
#pragma unroll
                for (int k = 0; k < 4; ++k)
                    xv[k] = __builtin_elementwise_max(up2(u0[k]) * sc2[k] + sh2[k], cl2);
#pragma unroll
                for (int k = 0; k < 4; ++k)
                    xv[4 + k] = __builtin_elementwise_max(up2(u1[k]) * sc2[4 + k] + sh2[4 + k], cl2);
            }
            int rb = rp[r] - beg;
            int re = rp[r + 1] - beg;
            const float* bemb_c = bemb + c0;
            if (cnt <= EMAX) {
                // uniform fast path: whole block's edges staged in LDS
                for (int j = rb; j < re; ++j) {
                    int ee = els[j];
                    int src = ee & 0x7FFFF;
                    int b = ee >> 19;
                    const unsigned short* sp = zin + (size_t)src * 128 + c0;
                    u32x4 s0 = *(const u32x4*)sp;
                    u32x4 s1 = *(const u32x4*)(sp + 8);
                    const f32x2* bp2 = (const f32x2*)(bemb_c + b * 128);
#pragma unroll
                    for (int k = 0; k < 4; ++k) {
                        f32x2 hv = __builtin_elementwise_max(up2(s0[k]) * sc2[k] + sh2[k], cl2);
                        xv[k] += __builtin_elementwise_max(hv + bp2[k], zero2);
                    }
#pragma unroll
                    for (int k = 0; k < 4; ++k) {
                        f32x2 hv = __builtin_elementwise_max(up2(s1[k]) * sc2[4 + k] + sh2[4 + k], cl2);
                        xv[4 + k] += __builtin_elementwise_max(hv + bp2[4 + k], zero2);
                    }
                }
            } else {
                for (int j = rb; j < re; ++j) {
                    int ee = ebuf[beg + j];
                    int src = ee & 0x7FFFF;
                    int b = ee >> 19;
                    const unsigned short* sp = zin + (size_t)src * 128 + c0;
                    u32x4 s0 = *(const u32x4*)sp;
                    u32x4 s1 = *(const u32x4*)(sp + 8);
                    const f32x2* bp2 = (const f32x2*)(bemb_c + b * 128);
#pragma unroll
                    for (int k = 0; k < 4; ++k) {
                        f32x2 hv = __builtin_elementwise_max(up2(s0[k]) * sc2[k] + sh2[k], cl2);
                        xv[k] += __builtin_elementwise_max(hv + bp2[k], zero2);
                    }
#pragma unroll
                    for (int k = 0; k < 4; ++k) {
                        f32x2 hv = __builtin_elementwise_max(up2(s1[k]) * sc2[4 + k] + sh2[4 + k], cl2);
                        xv[4 + k] += __builtin_elementwise_max(hv + bp2[4 + k], zero2);
                    }
                }
            }
        } else {
#pragma unroll
            for (int k = 0; k < 8; ++k) { xv[k].x = 0.f; xv[k].y = 0.f; }
        }
#pragma unroll
        for (int k = 0; k < 4; ++k) {
            *(ushort4*)(&xs[r][c0 + k * 4]) = make_ushort4(
                f2b(xv[2 * k].x), f2b(xv[2 * k].y), f2b(xv[2 * k + 1].x), f2b(xv[2 * k + 1].y));
        }
    }
    __syncthreads();

    int lrow = lane & 15;
    int lk8 = (lane >> 4) << 3;
    int rgrp = (lane >> 4) << 2;
    int wm = wv >> 2;   // 0..1  (M dimension)
    int wn = wv & 3;    // 0..3  (N dimension)

    f32x4 acc2[2][2];
#pragma unroll
    for (int mt = 0; mt < 2; ++mt)
#pragma unroll
        for (int t = 0; t < 2; ++t) acc2[mt][t] = (f32x4){0.f, 0.f, 0.f, 0.f};

#pragma unroll
    for (int half = 0; half < 2; ++half) {
        // GEMM1 for this N-half of t: cols half*128 .. half*128+128
        f32x4 acc1[2][2];
#pragma unroll
        for (int mt = 0; mt < 2; ++mt)
#pragma unroll
            for (int t = 0; t < 2; ++t) acc1[mt][t] = (f32x4){0.f, 0.f, 0.f, 0.f};

#pragma unroll
        for (int ks = 0; ks < 4; ++ks) {
            int kb = ks * 32 + lk8;
            short8v ah[2];
#pragma unroll
            for (int mt = 0; mt < 2; ++mt) {
                int mrow = (wm * 2 + mt) * 16 + lrow;
                ah[mt] = *(const short8v*)(&xs[mrow][kb]);
            }
#pragma unroll
            for (int t = 0; t < 2; ++t) {
                int nt = half * 8 + wn * 2 + t;
                size_t off = ((size_t)(nt * 4 + ks) * 64 + lane) * 8;
                short8v wh = *(const short8v*)(w1h + off);
#pragma unroll
                for (int mt = 0; mt < 2; ++mt)
                    acc1[mt][t] = MFMA(ah[mt], wh, acc1[mt][t]);
            }
        }

        if (half) __syncthreads();   // GEMM2-half0 done reading ts

        // epilogue: t = relu(acc1 + b1) -> ts bf16 (local cols 0..127)
#pragma unroll
        for (int t = 0; t < 2; ++t) {
            int coll = (wn * 2 + t) * 16 + lrow;
            float bb = b1[half * 128 + coll];
#pragma unroll
            for (int mt = 0; mt < 2; ++mt) {
                int row0 = (wm * 2 + mt) * 16 + rgrp;
#pragma unroll
                for (int r = 0; r < 4; ++r) {
                    ts[row0 + r][coll] = f2b(fmaxf(acc1[mt][t][r] + bb, 0.f));
                }
            }
        }
        __syncthreads();

        // GEMM2 partial: K-slice half*128..+128 of t
#pragma unroll
        for (int ksl = 0; ksl < 4; ++ksl) {
            int kb = ksl * 32 + lk8;
            short8v ah[2];
#pragma unroll
            for (int mt = 0; mt < 2; ++mt) {
                int mrow = (wm * 2 + mt) * 16 + lrow;
                ah[mt] = *(const short8v*)(&ts[mrow][kb]);
            }
#pragma unroll
            for (int t = 0; t < 2; ++t) {
                int nt = wn * 2 + t;
                int ks = half * 4 + ksl;
                size_t off = ((size_t)(nt * 8 + ks) * 64 + lane) * 8;
                short8v wh = *(const short8v*)(w2h + off);
#pragma unroll
                for (int mt = 0; mt < 2; ++mt)
                    acc2[mt][t] = MFMA(ah[mt], wh, acc2[mt][t]);
            }
        }
    }

    // final epilogue: zout = bf16(acc2 + b2), plus partial BN stats (on f32 values)
#pragma unroll
    for (int t = 0; t < 2; ++t) {
        int col = (wn * 2 + t) * 16 + lrow;
        float bb = b2[col];
        float s = 0.f, q = 0.f;
#pragma unroll
        for (int mt = 0; mt < 2; ++mt) {
#pragma unroll
            for (int r = 0; r < 4; ++r) {
                int row = rowBase + (wm * 2 + mt) * 16 + rgrp + r;
                if (row < N) {
                    float zv = acc2[mt][t][r] + bb;
                    zout[(size_t)row * 128 + col] = f2b(zv);
                    s += zv;
                    q += zv * zv;
                }
            }
        }
        s += __shfl_xor(s, 16, 64);
        s += __shfl_xor(s, 32, 64);
        q += __shfl_xor(q, 16, 64);
        q += __shfl_xor(q, 32, 64);
        if (lane < 16) {
            float* sp = stats_out + (size_t)(blockIdx.x & (STATS_NB - 1)) * 256;
            atomAddF(sp + col, s);
            atomAddF(sp + 128 + col, q);
        }
    }
}

// segmented pool over sorted batch; reduces last layer's stats itself.
__global__ __launch_bounds__(256) void pool_seg_kernel(const unsigned short* __restrict__ zb,
                                                       const int* __restrict__ batch,
                                                       const float* __restrict__ stats4,
                                                       const float* __restrict__ gamma4,
                                                       const float* __restrict__ beta4,
                                                       float* __restrict__ out, int N, int G,
                                                       float invN) {
    __shared__ float sums[256];
    __shared__ float scp[128], shp[128];
    int tid = threadIdx.x;
    {
        float s = 0.f;
#pragma unroll
        for (int i = 0; i < STATS_NB; ++i) s += stats4[i * 256 + tid];
        sums[tid] = s;
    }
    __syncthreads();
    if (tid < 128) {
        float mean = sums[tid] * invN;
        float var = sums[128 + tid] * invN - mean * mean;
        float sc = rsqrtf(var + 1e-5f) * gamma4[tid];
        scp[tid] = sc;
        shp[tid] = beta4[tid] - mean * sc;
    }
    __syncthreads();

    int g = blockIdx.x * 4 + (tid >> 6);
    if (g >= G) return;
    int lane = tid & 63;
    int lo = 0, hi = N;
    while (lo < hi) { int m = (lo + hi) >> 1; if (batch[m] < g) lo = m + 1; else hi = m; }
    int s = lo;
    hi = N;
    while (lo < hi) { int m = (lo + hi) >> 1; if (batch[m] < g + 1) lo = m + 1; else hi = m; }
    int e = lo;
    int c2 = lane * 2;
    float a0 = 0.f, a1 = 0.f;
    for (int i = s; i < e; ++i) {
        ushort2 u = *(const ushort2*)(zb + (size_t)i * 128 + c2);
        a0 += b2f(u.x);
        a1 += b2f(u.y);
    }
    float cntf = (float)(e - s);
    float o0 = scp[c2] * a0 + cntf * shp[c2];
    float o1 = scp[c2 + 1] * a1 + cntf * shp[c2 + 1];
    *(float2*)(out + (size_t)g * 128 + c2) = make_float2(o0, o1);
}

extern "C" void kernel_launch(void* const* d_in, const int* in_sizes, int n_in,
                              void* d_out, int out_size, void* d_ws, size_t ws_size,
                              hipStream_t stream) {
    const int* x        = (const int*)d_in[0];
    const int* ei       = (const int*)d_in[1];
    const int* eattr    = (const int*)d_in[2];
    const int* batch    = (const int*)d_in[3];
    const float* atom_e = (const float*)d_in[4];
    const float* bond_e = (const float*)d_in[5];
    const float* W1     = (const float*)d_in[6];
    const float* b1     = (const float*)d_in[7];
    const float* W2     = (const float*)d_in[8];
    const float* b2     = (const float*)d_in[9];
    const float* gamma  = (const float*)d_in[10];
    const float* beta   = (const float*)d_in[11];

    int N = in_sizes[0] / 9;
    int E = in_sizes[1] / 2;
    int G = out_size / 128;

    auto align = [](size_t v) { return (v + 255) & ~(size_t)255; };
    char* ws = (char*)d_ws;
    unsigned short* bufA = (unsigned short*)ws; ws += align((size_t)N * 128 * 2);
    unsigned short* bufB = (unsigned short*)ws; ws += align((size_t)N * 128 * 2);
    int* rowptr  = (int*)ws;                 ws += align((size_t)(N + 1) * 4);
    int* cursor  = (int*)ws;                 ws += align((size_t)N * 4);
    int* ebuf    = (int*)ws;                 ws += align((size_t)E * 4);
    int* bsum    = (int*)ws;                 ws += align((size_t)4096 * 4);
    unsigned short* w1h = (unsigned short*)ws; ws += align((size_t)LAYERS * 32768 * 2);
    unsigned short* w2h = (unsigned short*)ws; ws += align((size_t)LAYERS * 32768 * 2);
    float* stats = (float*)ws;               ws += align((size_t)LAYERS * STATS_NB * 256 * 4);

    float invN = 1.0f / (float)N;
    int nf4 = N * 32;
    int nb = (N + 1023) / 1024;

    init_h_kernel<<<(nf4 + 255) / 256, 256, 0, stream>>>(x, atom_e, bufA, N);

    // CSR build (once per call)
    hipMemsetAsync(cursor, 0, (size_t)N * 4, stream);
    hist_kernel<<<(E + 255) / 256, 256, 0, stream>>>(ei, cursor, E);
    scan_block_sum<<<nb, 256, 0, stream>>>(cursor, bsum, N);
    scan_bsums<<<1, 64, 0, stream>>>(bsum, nb);
    scan_write<<<nb, 256, 0, stream>>>(cursor, bsum, rowptr, N, E);
    scatter_kernel<<<(E + 255) / 256, 256, 0, stream>>>(ei, eattr, cursor, ebuf, E);

    // weight pre-pack + per-layer stats zero (once per call)
    pack_w1_kernel<<<(LAYERS * 4096 + 255) / 256, 256, 0, stream>>>(W1, w1h);
    pack_w2_kernel<<<(LAYERS * 4096 + 255) / 256, 256, 0, stream>>>(W2, w2h);
    hipMemsetAsync(stats, 0, (size_t)LAYERS * STATS_NB * 256 * 4, stream);

    unsigned short* zin = bufA;
    unsigned short* zout = bufB;
    for (int l = 0; l < LAYERS; ++l) {
        float clampv = (l == 0) ? -3.0e38f : 0.0f;
        float* st_prev = stats + (size_t)(l - 1) * STATS_NB * 256;   // unused for l==0
        float* st_out  = stats + (size_t)l * STATS_NB * 256;
        if (l == 0) {
            fused_mlp_kernel<true><<<(N + 63) / 64, 512, 0, stream>>>(
                zin, rowptr, ebuf, bond_e, nullptr, gamma, beta, invN, clampv,
                w1h + (size_t)l * 32768, w2h + (size_t)l * 32768,
                b1 + (size_t)l * 256, b2 + (size_t)l * 128,
                zout, st_out, N);
        } else {
            fused_mlp_kernel<false><<<(N + 63) / 64, 512, 0, stream>>>(
                zin, rowptr, ebuf, bond_e, st_prev,
                gamma + (size_t)(l - 1) * 128, beta + (size_t)(l - 1) * 128, invN, clampv,
                w1h + (size_t)l * 32768, w2h + (size_t)l * 32768,
                b1 + (size_t)l * 256, b2 + (size_t)l * 128,
                zout, st_out, N);
        }
        unsigned short* tmp = zin; zin = zout; zout = tmp;
    }

    // zin holds the last layer's raw z; pool applies BN4 (no relu) itself.
    pool_seg_kernel<<<(G + 3) / 4, 256, 0, stream>>>(
        zin, batch, stats + (size_t)(LAYERS - 1) * STATS_NB * 256,
        gamma + (size_t)(LAYERS - 1) * 128, beta + (size_t)(LAYERS - 1) * 128,
        (float*)d_out, N, G, invN);
}

// Round 19
// 960.937 us; speedup vs baseline: 1.2137x; 1.2137x over previous
//
#include <hip/hip_runtime.h>
#include <hip/hip_bf16.h>

#define LAYERS 5
#define STATS_NB 16
#define EMAX 160

typedef __attribute__((ext_vector_type(8))) short short8v;
typedef __attribute__((ext_vector_type(4))) float f32x4;
typedef __attribute__((ext_vector_type(4))) unsigned int u32x4;

#define MFMA(a, b, c) __builtin_amdgcn_mfma_f32_16x16x32_bf16(a, b, c, 0, 0, 0)

__device__ __forceinline__ void atomAddF(float* p, float v) {
    __hip_atomic_fetch_add(p, v, __ATOMIC_RELAXED, __HIP_MEMORY_SCOPE_AGENT);
}

// ---- bf16 helpers ----
__device__ __forceinline__ float b2f(unsigned short u) { return __uint_as_float(((unsigned)u) << 16); }
__device__ __forceinline__ unsigned short f2b(float f) {
    __hip_bfloat16 h = __float2bfloat16(f);
    unsigned short u;
    __builtin_memcpy(&u, &h, 2);
    return u;
}
__device__ __forceinline__ void st4(unsigned short* p, float4 v) {
    ushort4 u;
    u.x = f2b(v.x); u.y = f2b(v.y); u.z = f2b(v.z); u.w = f2b(v.w);
    *(ushort4*)p = u;
}
__device__ __forceinline__ void unpack8(u32x4 u, float* f) {
#pragma unroll
    for (int k = 0; k < 4; ++k) {
        unsigned int w = u[k];
        f[2 * k]     = __uint_as_float(w << 16);
        f[2 * k + 1] = __uint_as_float(w & 0xffff0000u);
    }
}

// h[i] = atom_emb[x[i*9]]  (bf16 store)
__global__ void init_h_kernel(const int* __restrict__ x, const float* __restrict__ atom_emb,
                              unsigned short* __restrict__ h, int N) {
    int tid = blockIdx.x * blockDim.x + threadIdx.x;
    if (tid >= N * 32) return;
    int i = tid >> 5;
    int c4 = (tid & 31) << 2;
    int a = x[i * 9];
    float4 v = *(const float4*)(atom_emb + a * 128 + c4);
    st4(h + (size_t)i * 128 + c4, v);
}

// ---------------- CSR build (once per call) ----------------
__global__ void hist_kernel(const int* __restrict__ ei, int* __restrict__ cnt, int E) {
    int e = blockIdx.x * blockDim.x + threadIdx.x;
    if (e < E) atomicAdd(&cnt[ei[E + e]], 1);
}

__global__ void scan_block_sum(const int* __restrict__ cnt, int* __restrict__ bsum, int N) {
    __shared__ int ls[256];
    int base = blockIdx.x * 1024;
    int tid = threadIdx.x;
    int s = 0;
#pragma unroll
    for (int j = 0; j < 4; ++j) {
        int i = base + tid * 4 + j;
        if (i < N) s += cnt[i];
    }
    ls[tid] = s;
    __syncthreads();
    for (int off = 128; off > 0; off >>= 1) {
        if (tid < off) ls[tid] += ls[tid + off];
        __syncthreads();
    }
    if (tid == 0) bsum[blockIdx.x] = ls[0];
}

__global__ void scan_bsums(int* __restrict__ bsum, int nb) {
    if (blockIdx.x == 0 && threadIdx.x == 0) {
        int acc = 0;
        for (int i = 0; i < nb; ++i) { int v = bsum[i]; bsum[i] = acc; acc += v; }
    }
}

__global__ void scan_write(int* __restrict__ cnt_cursor, const int* __restrict__ bsum,
                           int* __restrict__ rowptr, int N, int E) {
    __shared__ int ls[256];
    int base = blockIdx.x * 1024;
    int tid = threadIdx.x;
    int v[4];
    int s = 0;
#pragma unroll
    for (int j = 0; j < 4; ++j) {
        int i = base + tid * 4 + j;
        v[j] = (i < N) ? cnt_cursor[i] : 0;
        s += v[j];
    }
    ls[tid] = s;
    __syncthreads();
    if (tid == 0) {
        int acc = 0;
        for (int i = 0; i < 256; ++i) { int t = ls[i]; ls[i] = acc; acc += t; }
    }
    __syncthreads();
    int off = bsum[blockIdx.x] + ls[tid];
#pragma unroll
    for (int j = 0; j < 4; ++j) {
        int i = base + tid * 4 + j;
        if (i < N) {
            rowptr[i] = off;
            cnt_cursor[i] = off;
            off += v[j];
        }
    }
    if (blockIdx.x == 0 && tid == 0) rowptr[N] = E;
}

// ebuf[pos] = src | bond<<19   (src < 2^19, bond < 8)
__global__ void scatter_kernel(const int* __restrict__ ei, const int* __restrict__ eattr,
                               int* __restrict__ cursor, int* __restrict__ ebuf, int E) {
    int e = blockIdx.x * blockDim.x + threadIdx.x;
    if (e >= E) return;
    int d = ei[E + e];
    int pos = atomicAdd(&cursor[d], 1);
    ebuf[pos] = ei[e] | (eattr[e * 3] << 19);
}

// ---------------- weight pre-pack (plain bf16 RNE, 16x16 fragment order) ----------------
__global__ void pack_w1_kernel(const float* __restrict__ W1, unsigned short* __restrict__ wh) {
    int tid = blockIdx.x * blockDim.x + threadIdx.x;
    if (tid >= LAYERS * 16 * 4 * 64) return;
    int lane = tid & 63;
    int ks = (tid >> 6) & 3;
    int nt = (tid >> 8) & 15;
    int l  = tid >> 12;
    int n  = nt * 16 + (lane & 15);
    int k0 = ks * 32 + ((lane >> 4) << 3);
    unsigned short hh[8];
#pragma unroll
    for (int j = 0; j < 8; ++j)
        hh[j] = f2b(W1[((size_t)l * 128 + k0 + j) * 256 + n]);
    size_t off = (size_t)tid * 8;
    *(ushort4*)(wh + off)     = make_ushort4(hh[0], hh[1], hh[2], hh[3]);
    *(ushort4*)(wh + off + 4) = make_ushort4(hh[4], hh[5], hh[6], hh[7]);
}

__global__ void pack_w2_kernel(const float* __restrict__ W2, unsigned short* __restrict__ wh) {
    int tid = blockIdx.x * blockDim.x + threadIdx.x;
    if (tid >= LAYERS * 8 * 8 * 64) return;
    int lane = tid & 63;
    int ks = (tid >> 6) & 7;
    int nt = (tid >> 9) & 7;
    int l  = tid >> 12;
    int n  = nt * 16 + (lane & 15);
    int k0 = ks * 32 + ((lane >> 4) << 3);
    unsigned short hh[8];
#pragma unroll
    for (int j = 0; j < 8; ++j)
        hh[j] = f2b(W2[((size_t)l * 256 + k0 + j) * 128 + n]);
    size_t off = (size_t)tid * 8;
    *(ushort4*)(wh + off)     = make_ushort4(hh[0], hh[1], hh[2], hh[3]);
    *(ushort4*)(wh + off + 4) = make_ushort4(hh[4], hh[5], hh[6], hh[7]);
}

// ---------------- fused per-layer kernel ----------------
// BM=64 rows/block, 512 threads (8 waves, 2M x 4N wave grid), 16x16x32 MFMA
// (4 independent acc chains per wave — 32x32 single-chain was slower, r13).
// Plain bf16 weights (single MFMA/fragment): absmax 0.656 < 0.75 (r16/r17 measured).
// Gather math SCALAR f32 (r18's f32x2 rewrite forced xv[] into scratch:
// WRITE_SIZE 85->470MB at unchanged VGPR_Count — do NOT vectorize this phase).
// NOTE: launch_bounds MUST stay (512,6). (512,8) caps VGPR+AGPR at 64 and this
// kernel's ~72-reg floor then spills (confirmed twice: r11, r16).
template <bool FIRST>
__global__ __launch_bounds__(512, 6) void fused_mlp_kernel(
        const unsigned short* __restrict__ zin,
        const int* __restrict__ rowptr, const int* __restrict__ ebuf,
        const float* __restrict__ bond_emb,
        const float* __restrict__ stats_prev,
        const float* __restrict__ gamma_prev, const float* __restrict__ beta_prev,
        float invN, float clampv,
        const unsigned short* __restrict__ w1h,
        const unsigned short* __restrict__ w2h,
        const float* __restrict__ b1, const float* __restrict__ b2,
        unsigned short* __restrict__ zout, float* __restrict__ stats_out, int N) {
    __shared__ float bemb[8 * 128];
    __shared__ float scl[128], shl[128];
    __shared__ int els[EMAX];
    __shared__ int rp[65];
    __shared__ unsigned short xs[64][136];
    __shared__ unsigned short ts[64][136];

    int tid = threadIdx.x;
    int rowBase = blockIdx.x * 64;
    int lane = tid & 63;
    int wv = tid >> 6;          // 0..7

    // stage 1: bemb, raw stats sums, rowptr slice
    for (int i = tid; i < 1024; i += 512) bemb[i] = bond_emb[i];
    if (FIRST) {
        if (tid < 128) { scl[tid] = 1.f; shl[tid] = 0.f; }
    } else {
        if (tid < 256) {
            float s = 0.f;
#pragma unroll
            for (int i = 0; i < STATS_NB; ++i) s += stats_prev[i * 256 + tid];
            if (tid < 128) scl[tid] = s; else shl[tid - 128] = s;
        }
    }
    if (tid >= 256 && tid <= 320) {
        int t = tid - 256;
        int rr = rowBase + t;
        rp[t] = rowptr[rr < N ? rr : N];
    }
    __syncthreads();
    // stage 2: edge list; finalize BN affine
    int beg = rp[0];
    int cnt = rp[64] - beg;
    for (int i = tid; i < cnt && i < EMAX; i += 512) els[i] = ebuf[beg + i];
    if (!FIRST && tid < 128) {
        float S = scl[tid], Q = shl[tid];
        float mean = S * invN;
        float var = Q * invN - mean * mean;
        float sc = rsqrtf(var + 1e-5f) * gamma_prev[tid];
        scl[tid] = sc;
        shl[tid] = beta_prev[tid] - mean * sc;
    }
    __syncthreads();

    // phase 1: per-thread gather. thread -> (row, 16-col chunk)
    {
        int r = tid >> 3;
        int c0 = (tid & 7) << 4;
        int row = rowBase + r;
        float xv[16];
        if (row < N) {
            const unsigned short* hp = zin + (size_t)row * 128 + c0;
            u32x4 u0 = *(const u32x4*)hp;
            u32x4 u1 = *(const u32x4*)(hp + 8);
            float rv[16];
            unpack8(u0, rv);
            unpack8(u1, rv + 8);
#pragma unroll
            for (int i2 = 0; i2 < 16; ++i2)
                xv[i2] = fmaxf(fmaf(rv[i2], scl[c0 + i2], shl[c0 + i2]), clampv);
            int rb = rp[r] - beg;
            int re = rp[r + 1] - beg;
            const float* bemb_c = bemb + c0;
            if (cnt <= EMAX) {
                // block-uniform fast path: whole edge range staged in LDS
                for (int j = rb; j < re; ++j) {
                    int ee = els[j];
                    int src = ee & 0x7FFFF;
                    int b = ee >> 19;
                    const unsigned short* sp = zin + (size_t)src * 128 + c0;
                    u32x4 s0 = *(const u32x4*)sp;
                    u32x4 s1 = *(const u32x4*)(sp + 8);
                    float sv[16];
                    unpack8(s0, sv);
                    unpack8(s1, sv + 8);
                    const float* bp = bemb_c + b * 128;
#pragma unroll
                    for (int i2 = 0; i2 < 16; ++i2) {
                        float hv = fmaxf(fmaf(sv[i2], scl[c0 + i2], shl[c0 + i2]), clampv);
                        xv[i2] += fmaxf(hv + bp[i2], 0.f);
                    }
                }
            } else {
                for (int j = rb; j < re; ++j) {
                    int ee = ebuf[beg + j];
                    int src = ee & 0x7FFFF;
                    int b = ee >> 19;
                    const unsigned short* sp = zin + (size_t)src * 128 + c0;
                    u32x4 s0 = *(const u32x4*)sp;
                    u32x4 s1 = *(const u32x4*)(sp + 8);
                    float sv[16];
                    unpack8(s0, sv);
                    unpack8(s1, sv + 8);
                    const float* bp = bemb_c + b * 128;
#pragma unroll
                    for (int i2 = 0; i2 < 16; ++i2) {
                        float hv = fmaxf(fmaf(sv[i2], scl[c0 + i2], shl[c0 + i2]), clampv);
                        xv[i2] += fmaxf(hv + bp[i2], 0.f);
                    }
                }
            }
        } else {
#pragma unroll
            for (int i2 = 0; i2 < 16; ++i2) xv[i2] = 0.f;
        }
#pragma unroll
        for (int k = 0; k < 4; ++k) {
            *(ushort4*)(&xs[r][c0 + k * 4]) = make_ushort4(
                f2b(xv[k * 4 + 0]), f2b(xv[k * 4 + 1]), f2b(xv[k * 4 + 2]), f2b(xv[k * 4 + 3]));
        }
    }
    __syncthreads();

    int lrow = lane & 15;
    int lk8 = (lane >> 4) << 3;
    int rgrp = (lane >> 4) << 2;
    int wm = wv >> 2;   // 0..1  (M dimension)
    int wn = wv & 3;    // 0..3  (N dimension)

    f32x4 acc2[2][2];
#pragma unroll
    for (int mt = 0; mt < 2; ++mt)
#pragma unroll
        for (int t = 0; t < 2; ++t) acc2[mt][t] = (f32x4){0.f, 0.f, 0.f, 0.f};

#pragma unroll
    for (int half = 0; half < 2; ++half) {
        // GEMM1 for this N-half of t: cols half*128 .. half*128+128
        f32x4 acc1[2][2];
#pragma unroll
        for (int mt = 0; mt < 2; ++mt)
#pragma unroll
            for (int t = 0; t < 2; ++t) acc1[mt][t] = (f32x4){0.f, 0.f, 0.f, 0.f};

#pragma unroll
        for (int ks = 0; ks < 4; ++ks) {
            int kb = ks * 32 + lk8;
            short8v ah[2];
#pragma unroll
            for (int mt = 0; mt < 2; ++mt) {
                int mrow = (wm * 2 + mt) * 16 + lrow;
                ah[mt] = *(const short8v*)(&xs[mrow][kb]);
            }
#pragma unroll
            for (int t = 0; t < 2; ++t) {
                int nt = half * 8 + wn * 2 + t;
                size_t off = ((size_t)(nt * 4 + ks) * 64 + lane) * 8;
                short8v wh = *(const short8v*)(w1h + off);
#pragma unroll
                for (int mt = 0; mt < 2; ++mt)
                    acc1[mt][t] = MFMA(ah[mt], wh, acc1[mt][t]);
            }
        }

        if (half) __syncthreads();   // GEMM2-half0 done reading ts

        // epilogue: t = relu(acc1 + b1) -> ts bf16 (local cols 0..127)
#pragma unroll
        for (int t = 0; t < 2; ++t) {
            int coll = (wn * 2 + t) * 16 + lrow;
            float bb = b1[half * 128 + coll];
#pragma unroll
            for (int mt = 0; mt < 2; ++mt) {
                int row0 = (wm * 2 + mt) * 16 + rgrp;
#pragma unroll
                for (int r = 0; r < 4; ++r) {
                    ts[row0 + r][coll] = f2b(fmaxf(acc1[mt][t][r] + bb, 0.f));
                }
            }
        }
        __syncthreads();

        // GEMM2 partial: K-slice half*128..+128 of t
#pragma unroll
        for (int ksl = 0; ksl < 4; ++ksl) {
            int kb = ksl * 32 + lk8;
            short8v ah[2];
#pragma unroll
            for (int mt = 0; mt < 2; ++mt) {
                int mrow = (wm * 2 + mt) * 16 + lrow;
                ah[mt] = *(const short8v*)(&ts[mrow][kb]);
            }
#pragma unroll
            for (int t = 0; t < 2; ++t) {
                int nt = wn * 2 + t;
                int ks = half * 4 + ksl;
                size_t off = ((size_t)(nt * 8 + ks) * 64 + lane) * 8;
                short8v wh = *(const short8v*)(w2h + off);
#pragma unroll
                for (int mt = 0; mt < 2; ++mt)
                    acc2[mt][t] = MFMA(ah[mt], wh, acc2[mt][t]);
            }
        }
    }

    // final epilogue: zout = bf16(acc2 + b2), plus partial BN stats (on f32 values)
#pragma unroll
    for (int t = 0; t < 2; ++t) {
        int col = (wn * 2 + t) * 16 + lrow;
        float bb = b2[col];
        float s = 0.f, q = 0.f;
#pragma unroll
        for (int mt = 0; mt < 2; ++mt) {
#pragma unroll
            for (int r = 0; r < 4; ++r) {
                int row = rowBase + (wm * 2 + mt) * 16 + rgrp + r;
                if (row < N) {
                    float zv = acc2[mt][t][r] + bb;
                    zout[(size_t)row * 128 + col] = f2b(zv);
                    s += zv;
                    q += zv * zv;
                }
            }
        }
        s += __shfl_xor(s, 16, 64);
        s += __shfl_xor(s, 32, 64);
        q += __shfl_xor(q, 16, 64);
        q += __shfl_xor(q, 32, 64);
        if (lane < 16) {
            float* sp = stats_out + (size_t)(blockIdx.x & (STATS_NB - 1)) * 256;
            atomAddF(sp + col, s);
            atomAddF(sp + 128 + col, q);
        }
    }
}

// segmented pool over sorted batch; reduces last layer's stats itself.
__global__ __launch_bounds__(256) void pool_seg_kernel(const unsigned short* __restrict__ zb,
                                                       const int* __restrict__ batch,
                                                       const float* __restrict__ stats4,
                                                       const float* __restrict__ gamma4,
                                                       const float* __restrict__ beta4,
                                                       float* __restrict__ out, int N, int G,
                                                       float invN) {
    __shared__ float sums[256];
    __shared__ float scp[128], shp[128];
    int tid = threadIdx.x;
    {
        float s = 0.f;
#pragma unroll
        for (int i = 0; i < STATS_NB; ++i) s += stats4[i * 256 + tid];
        sums[tid] = s;
    }
    __syncthreads();
    if (tid < 128) {
        float mean = sums[tid] * invN;
        float var = sums[128 + tid] * invN - mean * mean;
        float sc = rsqrtf(var + 1e-5f) * gamma4[tid];
        scp[tid] = sc;
        shp[tid] = beta4[tid] - mean * sc;
    }
    __syncthreads();

    int g = blockIdx.x * 4 + (tid >> 6);
    if (g >= G) return;
    int lane = tid & 63;
    int lo = 0, hi = N;
    while (lo < hi) { int m = (lo + hi) >> 1; if (batch[m] < g) lo = m + 1; else hi = m; }
    int s = lo;
    hi = N;
    while (lo < hi) { int m = (lo + hi) >> 1; if (batch[m] < g + 1) lo = m + 1; else hi = m; }
    int e = lo;
    int c2 = lane * 2;
    float a0 = 0.f, a1 = 0.f;
    for (int i = s; i < e; ++i) {
        ushort2 u = *(const ushort2*)(zb + (size_t)i * 128 + c2);
        a0 += b2f(u.x);
        a1 += b2f(u.y);
    }
    float cntf = (float)(e - s);
    float o0 = scp[c2] * a0 + cntf * shp[c2];
    float o1 = scp[c2 + 1] * a1 + cntf * shp[c2 + 1];
    *(float2*)(out + (size_t)g * 128 + c2) = make_float2(o0, o1);
}

extern "C" void kernel_launch(void* const* d_in, const int* in_sizes, int n_in,
                              void* d_out, int out_size, void* d_ws, size_t ws_size,
                              hipStream_t stream) {
    const int* x        = (const int*)d_in[0];
    const int* ei       = (const int*)d_in[1];
    const int* eattr    = (const int*)d_in[2];
    const int* batch    = (const int*)d_in[3];
    const float* atom_e = (const float*)d_in[4];
    const float* bond_e = (const float*)d_in[5];
    const float* W1     = (const float*)d_in[6];
    const float* b1     = (const float*)d_in[7];
    const float* W2     = (const float*)d_in[8];
    const float* b2     = (const float*)d_in[9];
    const float* gamma  = (const float*)d_in[10];
    const float* beta   = (const float*)d_in[11];

    int N = in_sizes[0] / 9;
    int E = in_sizes[1] / 2;
    int G = out_size / 128;

    auto align = [](size_t v) { return (v + 255) & ~(size_t)255; };
    char* ws = (char*)d_ws;
    unsigned short* bufA = (unsigned short*)ws; ws += align((size_t)N * 128 * 2);
    unsigned short* bufB = (unsigned short*)ws; ws += align((size_t)N * 128 * 2);
    int* rowptr  = (int*)ws;                 ws += align((size_t)(N + 1) * 4);
    int* cursor  = (int*)ws;                 ws += align((size_t)N * 4);
    int* ebuf    = (int*)ws;                 ws += align((size_t)E * 4);
    int* bsum    = (int*)ws;                 ws += align((size_t)4096 * 4);
    unsigned short* w1h = (unsigned short*)ws; ws += align((size_t)LAYERS * 32768 * 2);
    unsigned short* w2h = (unsigned short*)ws; ws += align((size_t)LAYERS * 32768 * 2);
    float* stats = (float*)ws;               ws += align((size_t)LAYERS * STATS_NB * 256 * 4);

    float invN = 1.0f / (float)N;
    int nf4 = N * 32;
    int nb = (N + 1023) / 1024;

    init_h_kernel<<<(nf4 + 255) / 256, 256, 0, stream>>>(x, atom_e, bufA, N);

    // CSR build (once per call)
    hipMemsetAsync(cursor, 0, (size_t)N * 4, stream);
    hist_kernel<<<(E + 255) / 256, 256, 0, stream>>>(ei, cursor, E);
    scan_block_sum<<<nb, 256, 0, stream>>>(cursor, bsum, N);
    scan_bsums<<<1, 64, 0, stream>>>(bsum, nb);
    scan_write<<<nb, 256, 0, stream>>>(cursor, bsum, rowptr, N, E);
    scatter_kernel<<<(E + 255) / 256, 256, 0, stream>>>(ei, eattr, cursor, ebuf, E);

    // weight pre-pack + per-layer stats zero (once per call)
    pack_w1_kernel<<<(LAYERS * 4096 + 255) / 256, 256, 0, stream>>>(W1, w1h);
    pack_w2_kernel<<<(LAYERS * 4096 + 255) / 256, 256, 0, stream>>>(W2, w2h);
    hipMemsetAsync(stats, 0, (size_t)LAYERS * STATS_NB * 256 * 4, stream);

    unsigned short* zin = bufA;
    unsigned short* zout = bufB;
    for (int l = 0; l < LAYERS; ++l) {
        float clampv = (l == 0) ? -3.0e38f : 0.0f;
        float* st_prev = stats + (size_t)(l - 1) * STATS_NB * 256;   // unused for l==0
        float* st_out  = stats + (size_t)l * STATS_NB * 256;
        if (l == 0) {
            fused_mlp_kernel<true><<<(N + 63) / 64, 512, 0, stream>>>(
                zin, rowptr, ebuf, bond_e, nullptr, gamma, beta, invN, clampv,
                w1h + (size_t)l * 32768, w2h + (size_t)l * 32768,
                b1 + (size_t)l * 256, b2 + (size_t)l * 128,
                zout, st_out, N);
        } else {
            fused_mlp_kernel<false><<<(N + 63) / 64, 512, 0, stream>>>(
                zin, rowptr, ebuf, bond_e, st_prev,
                gamma + (size_t)(l - 1) * 128, beta + (size_t)(l - 1) * 128, invN, clampv,
                w1h + (size_t)l * 32768, w2h + (size_t)l * 32768,
                b1 + (size_t)l * 256, b2 + (size_t)l * 128,
                zout, st_out, N);
        }
        unsigned short* tmp = zin; zin = zout; zout = tmp;
    }

    // zin holds the last layer's raw z; pool applies BN4 (no relu) itself.
    pool_seg_kernel<<<(G + 3) / 4, 256, 0, stream>>>(
        zin, batch, stats + (size_t)(LAYERS - 1) * STATS_NB * 256,
        gamma + (size_t)(LAYERS - 1) * 128, beta + (size_t)(LAYERS - 1) * 128,
        (float*)d_out, N, G, invN);
}

// Round 20
// 794.215 us; speedup vs baseline: 1.4684x; 1.2099x over previous
//
#include <hip/hip_runtime.h>
#include <hip/hip_bf16.h>

#define LAYERS 5
#define STATS_NB 16
#define EMAX 160

typedef __attribute__((ext_vector_type(8))) short short8v;
typedef __attribute__((ext_vector_type(4))) float f32x4;
typedef __attribute__((ext_vector_type(4))) unsigned int u32x4;

#define MFMA(a, b, c) __builtin_amdgcn_mfma_f32_16x16x32_bf16(a, b, c, 0, 0, 0)

__device__ __forceinline__ void atomAddF(float* p, float v) {
    __hip_atomic_fetch_add(p, v, __ATOMIC_RELAXED, __HIP_MEMORY_SCOPE_AGENT);
}

// ---- bf16 helpers ----
__device__ __forceinline__ float b2f(unsigned short u) { return __uint_as_float(((unsigned)u) << 16); }
__device__ __forceinline__ unsigned short f2b(float f) {
    __hip_bfloat16 h = __float2bfloat16(f);
    unsigned short u;
    __builtin_memcpy(&u, &h, 2);
    return u;
}
__device__ __forceinline__ void st4(unsigned short* p, float4 v) {
    ushort4 u;
    u.x = f2b(v.x); u.y = f2b(v.y); u.z = f2b(v.z); u.w = f2b(v.w);
    *(ushort4*)p = u;
}
__device__ __forceinline__ void unpack8(u32x4 u, float* f) {
#pragma unroll
    for (int k = 0; k < 4; ++k) {
        unsigned int w = u[k];
        f[2 * k]     = __uint_as_float(w << 16);
        f[2 * k + 1] = __uint_as_float(w & 0xffff0000u);
    }
}

// h[i] = atom_emb[x[i*9]]  (bf16 store)
__global__ void init_h_kernel(const int* __restrict__ x, const float* __restrict__ atom_emb,
                              unsigned short* __restrict__ h, int N) {
    int tid = blockIdx.x * blockDim.x + threadIdx.x;
    if (tid >= N * 32) return;
    int i = tid >> 5;
    int c4 = (tid & 31) << 2;
    int a = x[i * 9];
    float4 v = *(const float4*)(atom_emb + a * 128 + c4);
    st4(h + (size_t)i * 128 + c4, v);
}

// ---------------- CSR build (once per call) ----------------
__global__ void hist_kernel(const int* __restrict__ ei, int* __restrict__ cnt, int E) {
    int e = blockIdx.x * blockDim.x + threadIdx.x;
    if (e < E) atomicAdd(&cnt[ei[E + e]], 1);
}

__global__ void scan_block_sum(const int* __restrict__ cnt, int* __restrict__ bsum, int N) {
    __shared__ int ls[256];
    int base = blockIdx.x * 1024;
    int tid = threadIdx.x;
    int s = 0;
#pragma unroll
    for (int j = 0; j < 4; ++j) {
        int i = base + tid * 4 + j;
        if (i < N) s += cnt[i];
    }
    ls[tid] = s;
    __syncthreads();
    for (int off = 128; off > 0; off >>= 1) {
        if (tid < off) ls[tid] += ls[tid + off];
        __syncthreads();
    }
    if (tid == 0) bsum[blockIdx.x] = ls[0];
}

// parallel exclusive scan of block sums (single block, Hillis-Steele, chunk-carried)
__global__ void scan_bsums_par(int* __restrict__ bsum, int nb) {
    __shared__ int ls[512];
    __shared__ int carryS;
    int tid = threadIdx.x;
    if (tid == 0) carryS = 0;
    __syncthreads();
    for (int base = 0; base < nb; base += 512) {
        int i = base + tid;
        int v = (i < nb) ? bsum[i] : 0;
        ls[tid] = v;
        __syncthreads();
        for (int off = 1; off < 512; off <<= 1) {
            int t = (tid >= off) ? ls[tid - off] : 0;
            __syncthreads();
            ls[tid] += t;
            __syncthreads();
        }
        int incl = ls[tid];
        if (i < nb) bsum[i] = carryS + (incl - v);
        __syncthreads();
        if (tid == 511) carryS += ls[511];
        __syncthreads();
    }
}

__global__ void scan_write(int* __restrict__ cnt_cursor, const int* __restrict__ bsum,
                           int* __restrict__ rowptr, int N, int E) {
    __shared__ int ls[256];
    int base = blockIdx.x * 1024;
    int tid = threadIdx.x;
    int v[4];
    int s = 0;
#pragma unroll
    for (int j = 0; j < 4; ++j) {
        int i = base + tid * 4 + j;
        v[j] = (i < N) ? cnt_cursor[i] : 0;
        s += v[j];
    }
    ls[tid] = s;
    __syncthreads();
    if (tid == 0) {
        int acc = 0;
        for (int i = 0; i < 256; ++i) { int t = ls[i]; ls[i] = acc; acc += t; }
    }
    __syncthreads();
    int off = bsum[blockIdx.x] + ls[tid];
#pragma unroll
    for (int j = 0; j < 4; ++j) {
        int i = base + tid * 4 + j;
        if (i < N) {
            rowptr[i] = off;
            cnt_cursor[i] = off;
            off += v[j];
        }
    }
    if (blockIdx.x == 0 && tid == 0) rowptr[N] = E;
}

// ebuf[pos] = src | bond<<19   (src < 2^19, bond < 8)
__global__ void scatter_kernel(const int* __restrict__ ei, const int* __restrict__ eattr,
                               int* __restrict__ cursor, int* __restrict__ ebuf, int E) {
    int e = blockIdx.x * blockDim.x + threadIdx.x;
    if (e >= E) return;
    int d = ei[E + e];
    int pos = atomicAdd(&cursor[d], 1);
    ebuf[pos] = ei[e] | (eattr[e * 3] << 19);
}

// ---------------- weight pre-pack (plain bf16 RNE, 16x16 fragment order) ----------------
__global__ void pack_w1_kernel(const float* __restrict__ W1, unsigned short* __restrict__ wh) {
    int tid = blockIdx.x * blockDim.x + threadIdx.x;
    if (tid >= LAYERS * 16 * 4 * 64) return;
    int lane = tid & 63;
    int ks = (tid >> 6) & 3;
    int nt = (tid >> 8) & 15;
    int l  = tid >> 12;
    int n  = nt * 16 + (lane & 15);
    int k0 = ks * 32 + ((lane >> 4) << 3);
    unsigned short hh[8];
#pragma unroll
    for (int j = 0; j < 8; ++j)
        hh[j] = f2b(W1[((size_t)l * 128 + k0 + j) * 256 + n]);
    size_t off = (size_t)tid * 8;
    *(ushort4*)(wh + off)     = make_ushort4(hh[0], hh[1], hh[2], hh[3]);
    *(ushort4*)(wh + off + 4) = make_ushort4(hh[4], hh[5], hh[6], hh[7]);
}

__global__ void pack_w2_kernel(const float* __restrict__ W2, unsigned short* __restrict__ wh) {
    int tid = blockIdx.x * blockDim.x + threadIdx.x;
    if (tid >= LAYERS * 8 * 8 * 64) return;
    int lane = tid & 63;
    int ks = (tid >> 6) & 7;
    int nt = (tid >> 9) & 7;
    int l  = tid >> 12;
    int n  = nt * 16 + (lane & 15);
    int k0 = ks * 32 + ((lane >> 4) << 3);
    unsigned short hh[8];
#pragma unroll
    for (int j = 0; j < 8; ++j)
        hh[j] = f2b(W2[((size_t)l * 256 + k0 + j) * 128 + n]);
    size_t off = (size_t)tid * 8;
    *(ushort4*)(wh + off)     = make_ushort4(hh[0], hh[1], hh[2], hh[3]);
    *(ushort4*)(wh + off + 4) = make_ushort4(hh[4], hh[5], hh[6], hh[7]);
}

// ---------------- fused per-layer kernel ----------------
// EXACT r17 form. BM=64 rows/block, 512 threads (8 waves, 2M x 4N), 16x16x32 MFMA.
// Plain bf16 weights (single MFMA/fragment): absmax 0.656 < 0.75 (r16/r17 measured).
// Gather phase MUST stay in this exact scalar single-loop form:
//  - f32x2/ext-vector math -> scratch (r18: WRITE 85->470MB)
//  - duplicated els/fallback loops -> scratch (r19: WRITE 85->257MB)
// launch_bounds MUST stay (512,6): (512,8) caps regs at 64, ~72-reg floor spills (r11,r16).
template <bool FIRST>
__global__ __launch_bounds__(512, 6) void fused_mlp_kernel(
        const unsigned short* __restrict__ zin,
        const int* __restrict__ rowptr, const int* __restrict__ ebuf,
        const float* __restrict__ bond_emb,
        const float* __restrict__ stats_prev,
        const float* __restrict__ gamma_prev, const float* __restrict__ beta_prev,
        float invN, float clampv,
        const unsigned short* __restrict__ w1h,
        const unsigned short* __restrict__ w2h,
        const float* __restrict__ b1, const float* __restrict__ b2,
        unsigned short* __restrict__ zout, float* __restrict__ stats_out, int N) {
    __shared__ float bemb[8 * 128];
    __shared__ float scl[128], shl[128];
    __shared__ int els[EMAX];
    __shared__ int rp[65];
    __shared__ unsigned short xs[64][136];
    __shared__ unsigned short ts[64][136];

    int tid = threadIdx.x;
    int rowBase = blockIdx.x * 64;
    int lane = tid & 63;
    int wv = tid >> 6;          // 0..7

    // stage 1: bemb, raw stats sums, rowptr slice
    for (int i = tid; i < 1024; i += 512) bemb[i] = bond_emb[i];
    if (FIRST) {
        if (tid < 128) { scl[tid] = 1.f; shl[tid] = 0.f; }
    } else {
        if (tid < 256) {
            float s = 0.f;
#pragma unroll
            for (int i = 0; i < STATS_NB; ++i) s += stats_prev[i * 256 + tid];
            if (tid < 128) scl[tid] = s; else shl[tid - 128] = s;
        }
    }
    if (tid >= 256 && tid <= 320) {
        int t = tid - 256;
        int rr = rowBase + t;
        rp[t] = rowptr[rr < N ? rr : N];
    }
    __syncthreads();
    // stage 2: edge list; finalize BN affine
    int beg = rp[0];
    int cnt = rp[64] - beg;
    for (int i = tid; i < cnt && i < EMAX; i += 512) els[i] = ebuf[beg + i];
    if (!FIRST && tid < 128) {
        float S = scl[tid], Q = shl[tid];
        float mean = S * invN;
        float var = Q * invN - mean * mean;
        float sc = rsqrtf(var + 1e-5f) * gamma_prev[tid];
        scl[tid] = sc;
        shl[tid] = beta_prev[tid] - mean * sc;
    }
    __syncthreads();

    // phase 1: per-thread gather. thread -> (row, 16-col chunk)
    {
        int r = tid >> 3;
        int c0 = (tid & 7) << 4;
        int row = rowBase + r;
        float xv[16];
        if (row < N) {
            const unsigned short* hp = zin + (size_t)row * 128 + c0;
            u32x4 u0 = *(const u32x4*)hp;
            u32x4 u1 = *(const u32x4*)(hp + 8);
            float rv[16];
            unpack8(u0, rv);
            unpack8(u1, rv + 8);
#pragma unroll
            for (int i2 = 0; i2 < 16; ++i2)
                xv[i2] = fmaxf(fmaf(rv[i2], scl[c0 + i2], shl[c0 + i2]), clampv);
            int rb = rp[r] - beg;
            int re = rp[r + 1] - beg;
            const float* bemb_c = bemb + c0;
            for (int j = rb; j < re; ++j) {
                int ee = (j < EMAX) ? els[j] : ebuf[beg + j];
                int src = ee & 0x7FFFF;
                int b = ee >> 19;
                const unsigned short* sp = zin + (size_t)src * 128 + c0;
                u32x4 s0 = *(const u32x4*)sp;
                u32x4 s1 = *(const u32x4*)(sp + 8);
                float sv[16];
                unpack8(s0, sv);
                unpack8(s1, sv + 8);
                const float* bp = bemb_c + b * 128;
#pragma unroll
                for (int i2 = 0; i2 < 16; ++i2) {
                    float hv = fmaxf(fmaf(sv[i2], scl[c0 + i2], shl[c0 + i2]), clampv);
                    xv[i2] += fmaxf(hv + bp[i2], 0.f);
                }
            }
        } else {
#pragma unroll
            for (int i2 = 0; i2 < 16; ++i2) xv[i2] = 0.f;
        }
#pragma unroll
        for (int k = 0; k < 4; ++k) {
            *(ushort4*)(&xs[r][c0 + k * 4]) = make_ushort4(
                f2b(xv[k * 4 + 0]), f2b(xv[k * 4 + 1]), f2b(xv[k * 4 + 2]), f2b(xv[k * 4 + 3]));
        }
    }
    __syncthreads();

    int lrow = lane & 15;
    int lk8 = (lane >> 4) << 3;
    int rgrp = (lane >> 4) << 2;
    int wm = wv >> 2;   // 0..1  (M dimension)
    int wn = wv & 3;    // 0..3  (N dimension)

    f32x4 acc2[2][2];
#pragma unroll
    for (int mt = 0; mt < 2; ++mt)
#pragma unroll
        for (int t = 0; t < 2; ++t) acc2[mt][t] = (f32x4){0.f, 0.f, 0.f, 0.f};

#pragma unroll
    for (int half = 0; half < 2; ++half) {
        // GEMM1 for this N-half of t: cols half*128 .. half*128+128
        f32x4 acc1[2][2];
#pragma unroll
        for (int mt = 0; mt < 2; ++mt)
#pragma unroll
            for (int t = 0; t < 2; ++t) acc1[mt][t] = (f32x4){0.f, 0.f, 0.f, 0.f};

#pragma unroll
        for (int ks = 0; ks < 4; ++ks) {
            int kb = ks * 32 + lk8;
            short8v ah[2];
#pragma unroll
            for (int mt = 0; mt < 2; ++mt) {
                int mrow = (wm * 2 + mt) * 16 + lrow;
                ah[mt] = *(const short8v*)(&xs[mrow][kb]);
            }
#pragma unroll
            for (int t = 0; t < 2; ++t) {
                int nt = half * 8 + wn * 2 + t;
                size_t off = ((size_t)(nt * 4 + ks) * 64 + lane) * 8;
                short8v wh = *(const short8v*)(w1h + off);
#pragma unroll
                for (int mt = 0; mt < 2; ++mt)
                    acc1[mt][t] = MFMA(ah[mt], wh, acc1[mt][t]);
            }
        }

        if (half) __syncthreads();   // GEMM2-half0 done reading ts

        // epilogue: t = relu(acc1 + b1) -> ts bf16 (local cols 0..127)
#pragma unroll
        for (int t = 0; t < 2; ++t) {
            int coll = (wn * 2 + t) * 16 + lrow;
            float bb = b1[half * 128 + coll];
#pragma unroll
            for (int mt = 0; mt < 2; ++mt) {
                int row0 = (wm * 2 + mt) * 16 + rgrp;
#pragma unroll
                for (int r = 0; r < 4; ++r) {
                    ts[row0 + r][coll] = f2b(fmaxf(acc1[mt][t][r] + bb, 0.f));
                }
            }
        }
        __syncthreads();

        // GEMM2 partial: K-slice half*128..+128 of t
#pragma unroll
        for (int ksl = 0; ksl < 4; ++ksl) {
            int kb = ksl * 32 + lk8;
            short8v ah[2];
#pragma unroll
            for (int mt = 0; mt < 2; ++mt) {
                int mrow = (wm * 2 + mt) * 16 + lrow;
                ah[mt] = *(const short8v*)(&ts[mrow][kb]);
            }
#pragma unroll
            for (int t = 0; t < 2; ++t) {
                int nt = wn * 2 + t;
                int ks = half * 4 + ksl;
                size_t off = ((size_t)(nt * 8 + ks) * 64 + lane) * 8;
                short8v wh = *(const short8v*)(w2h + off);
#pragma unroll
                for (int mt = 0; mt < 2; ++mt)
                    acc2[mt][t] = MFMA(ah[mt], wh, acc2[mt][t]);
            }
        }
    }

    // final epilogue: zout = bf16(acc2 + b2), plus partial BN stats (on f32 values)
#pragma unroll
    for (int t = 0; t < 2; ++t) {
        int col = (wn * 2 + t) * 16 + lrow;
        float bb = b2[col];
        float s = 0.f, q = 0.f;
#pragma unroll
        for (int mt = 0; mt < 2; ++mt) {
#pragma unroll
            for (int r = 0; r < 4; ++r) {
                int row = rowBase + (wm * 2 + mt) * 16 + rgrp + r;
                if (row < N) {
                    float zv = acc2[mt][t][r] + bb;
                    zout[(size_t)row * 128 + col] = f2b(zv);
                    s += zv;
                    q += zv * zv;
                }
            }
        }
        s += __shfl_xor(s, 16, 64);
        s += __shfl_xor(s, 32, 64);
        q += __shfl_xor(q, 16, 64);
        q += __shfl_xor(q, 32, 64);
        if (lane < 16) {
            float* sp = stats_out + (size_t)(blockIdx.x & (STATS_NB - 1)) * 256;
            atomAddF(sp + col, s);
            atomAddF(sp + 128 + col, q);
        }
    }
}

// segmented pool over sorted batch; reduces last layer's stats itself.
__global__ __launch_bounds__(256) void pool_seg_kernel(const unsigned short* __restrict__ zb,
                                                       const int* __restrict__ batch,
                                                       const float* __restrict__ stats4,
                                                       const float* __restrict__ gamma4,
                                                       const float* __restrict__ beta4,
                                                       float* __restrict__ out, int N, int G,
                                                       float invN) {
    __shared__ float sums[256];
    __shared__ float scp[128], shp[128];
    int tid = threadIdx.x;
    {
        float s = 0.f;
#pragma unroll
        for (int i = 0; i < STATS_NB; ++i) s += stats4[i * 256 + tid];
        sums[tid] = s;
    }
    __syncthreads();
    if (tid < 128) {
        float mean = sums[tid] * invN;
        float var = sums[128 + tid] * invN - mean * mean;
        float sc = rsqrtf(var + 1e-5f) * gamma4[tid];
        scp[tid] = sc;
        shp[tid] = beta4[tid] - mean * sc;
    }
    __syncthreads();

    int g = blockIdx.x * 4 + (tid >> 6);
    if (g >= G) return;
    int lane = tid & 63;
    int lo = 0, hi = N;
    while (lo < hi) { int m = (lo + hi) >> 1; if (batch[m] < g) lo = m + 1; else hi = m; }
    int s = lo;
    hi = N;
    while (lo < hi) { int m = (lo + hi) >> 1; if (batch[m] < g + 1) lo = m + 1; else hi = m; }
    int e = lo;
    int c2 = lane * 2;
    float a0 = 0.f, a1 = 0.f;
    for (int i = s; i < e; ++i) {
        ushort2 u = *(const ushort2*)(zb + (size_t)i * 128 + c2);
        a0 += b2f(u.x);
        a1 += b2f(u.y);
    }
    float cntf = (float)(e - s);
    float o0 = scp[c2] * a0 + cntf * shp[c2];
    float o1 = scp[c2 + 1] * a1 + cntf * shp[c2 + 1];
    *(float2*)(out + (size_t)g * 128 + c2) = make_float2(o0, o1);
}

extern "C" void kernel_launch(void* const* d_in, const int* in_sizes, int n_in,
                              void* d_out, int out_size, void* d_ws, size_t ws_size,
                              hipStream_t stream) {
    const int* x        = (const int*)d_in[0];
    const int* ei       = (const int*)d_in[1];
    const int* eattr    = (const int*)d_in[2];
    const int* batch    = (const int*)d_in[3];
    const float* atom_e = (const float*)d_in[4];
    const float* bond_e = (const float*)d_in[5];
    const float* W1     = (const float*)d_in[6];
    const float* b1     = (const float*)d_in[7];
    const float* W2     = (const float*)d_in[8];
    const float* b2     = (const float*)d_in[9];
    const float* gamma  = (const float*)d_in[10];
    const float* beta   = (const float*)d_in[11];

    int N = in_sizes[0] / 9;
    int E = in_sizes[1] / 2;
    int G = out_size / 128;

    auto align = [](size_t v) { return (v + 255) & ~(size_t)255; };
    char* ws = (char*)d_ws;
    unsigned short* bufA = (unsigned short*)ws; ws += align((size_t)N * 128 * 2);
    unsigned short* bufB = (unsigned short*)ws; ws += align((size_t)N * 128 * 2);
    int* rowptr  = (int*)ws;                 ws += align((size_t)(N + 1) * 4);
    int* cursor  = (int*)ws;                 ws += align((size_t)N * 4);
    int* ebuf    = (int*)ws;                 ws += align((size_t)E * 4);
    int* bsum    = (int*)ws;                 ws += align((size_t)4096 * 4);
    unsigned short* w1h = (unsigned short*)ws; ws += align((size_t)LAYERS * 32768 * 2);
    unsigned short* w2h = (unsigned short*)ws; ws += align((size_t)LAYERS * 32768 * 2);
    float* stats = (float*)ws;               ws += align((size_t)LAYERS * STATS_NB * 256 * 4);

    float invN = 1.0f / (float)N;
    int nf4 = N * 32;
    int nb = (N + 1023) / 1024;

    init_h_kernel<<<(nf4 + 255) / 256, 256, 0, stream>>>(x, atom_e, bufA, N);

    // CSR build (once per call)
    hipMemsetAsync(cursor, 0, (size_t)N * 4, stream);
    hist_kernel<<<(E + 255) / 256, 256, 0, stream>>>(ei, cursor, E);
    scan_block_sum<<<nb, 256, 0, stream>>>(cursor, bsum, N);
    scan_bsums_par<<<1, 512, 0, stream>>>(bsum, nb);
    scan_write<<<nb, 256, 0, stream>>>(cursor, bsum, rowptr, N, E);
    scatter_kernel<<<(E + 255) / 256, 256, 0, stream>>>(ei, eattr, cursor, ebuf, E);

    // weight pre-pack + per-layer stats zero (once per call)
    pack_w1_kernel<<<(LAYERS * 4096 + 255) / 256, 256, 0, stream>>>(W1, w1h);
    pack_w2_kernel<<<(LAYERS * 4096 + 255) / 256, 256, 0, stream>>>(W2, w2h);
    hipMemsetAsync(stats, 0, (size_t)LAYERS * STATS_NB * 256 * 4, stream);

    unsigned short* zin = bufA;
    unsigned short* zout = bufB;
    for (int l = 0; l < LAYERS; ++l) {
        float clampv = (l == 0) ? -3.0e38f : 0.0f;
        float* st_prev = stats + (size_t)(l - 1) * STATS_NB * 256;   // unused for l==0
        float* st_out  = stats + (size_t)l * STATS_NB * 256;
        if (l == 0) {
            fused_mlp_kernel<true><<<(N + 63) / 64, 512, 0, stream>>>(
                zin, rowptr, ebuf, bond_e, nullptr, gamma, beta, invN, clampv,
                w1h + (size_t)l * 32768, w2h + (size_t)l * 32768,
                b1 + (size_t)l * 256, b2 + (size_t)l * 128,
                zout, st_out, N);
        } else {
            fused_mlp_kernel<false><<<(N + 63) / 64, 512, 0, stream>>>(
                zin, rowptr, ebuf, bond_e, st_prev,
                gamma + (size_t)(l - 1) * 128, beta + (size_t)(l - 1) * 128, invN, clampv,
                w1h + (size_t)l * 32768, w2h + (size_t)l * 32768,
                b1 + (size_t)l * 256, b2 + (size_t)l * 128,
                zout, st_out, N);
        }
        unsigned short* tmp = zin; zin = zout; zout = tmp;
    }

    // zin holds the last layer's raw z; pool applies BN4 (no relu) itself.
    pool_seg_kernel<<<(G + 3) / 4, 256, 0, stream>>>(
        zin, batch, stats + (size_t)(LAYERS - 1) * STATS_NB * 256,
        gamma + (size_t)(LAYERS - 1) * 128, beta + (size_t)(LAYERS - 1) * 128,
        (float*)d_out, N, G, invN);
}